// Round 8
// baseline (38.081 us; speedup 1.0000x reference)
//
#include <hip/hip_runtime.h>
#include <math.h>

// Problem constants
#define BB 4096      // batch
#define DD 512       // feature dim
#define CC 1000      // num classes

typedef __attribute__((ext_vector_type(8))) short short8;
typedef __attribute__((ext_vector_type(4))) float f32x4;

// ---------------- ws layout (float slots) ----------------
#define OFF_ABF  0              // 4096x512 bf16 = 1048576 float slots
#define OFF_EBF  1048576        // 1024x512 bf16 = 262144
#define OFF_ESQ  1310720        // 1024
#define OFF_ASQ  1311744        // 4096
#define OFF_DREF 1315840        // 4096
#define OFF_PMIN 1319936        // 4096
#define OFF_CEP  1324032        // 1536
#define OFF_TRP  1327104        // 512

__device__ __forceinline__ unsigned short f2bf(float x) {
    unsigned u = __float_as_uint(x);
    unsigned r = (u + 0x7FFFu + ((u >> 16) & 1u)) >> 16;   // RNE
    return (unsigned short)r;
}

// ---------------------------------------------------------------------------
// K1: 2176 blocks x 512 threads, all roles independent (no cross-role deps):
//   bid < 1536           : CE, 8 rows/block
//   1536 <= bid < 2048   : triplet + asq + exact dref + anchor->bf16 + pmin=INF
//   2048 <= bid < 2176   : exemplar->bf16 (padded) + esq
// ---------------------------------------------------------------------------
__global__ __launch_bounds__(512) void k1_kernel(
    const float* __restrict__ a, const float* __restrict__ p,
    const float* __restrict__ n, const float* __restrict__ ex,
    const float* __restrict__ outp,
    const int* __restrict__ la, const int* __restrict__ ln,
    unsigned short* __restrict__ Abf, unsigned short* __restrict__ Ebf,
    float* __restrict__ esq, float* __restrict__ asq,
    float* __restrict__ dref, float* __restrict__ tr_part,
    float* __restrict__ pmin, float* __restrict__ ce_part)
{
    __shared__ float ps[8];
    const int bid = blockIdx.x;
    const int tid = threadIdx.x;
    const int w = tid >> 6, lane = tid & 63;

    if (bid < 1536) {
        // =================== CE: one wave per row, float4 loads ===================
        const int r = bid * 8 + w;                              // [0,12288)
        const int label = (r < 2 * BB) ? la[r & (BB - 1)] : ln[r - 2 * BB];
        const float4* row4 = (const float4*)(outp + (size_t)r * CC);   // 250 float4
        float4 v[4];
#pragma unroll
        for (int k = 0; k < 4; k++) {
            int j4 = lane + k * 64;
            v[k] = (j4 < 250) ? row4[j4]
                              : make_float4(-INFINITY, -INFINITY, -INFINITY, -INFINITY);
        }
        float m = -INFINITY;
#pragma unroll
        for (int k = 0; k < 4; k++)
            m = fmaxf(m, fmaxf(fmaxf(v[k].x, v[k].y), fmaxf(v[k].z, v[k].w)));
        for (int off = 32; off; off >>= 1) m = fmaxf(m, __shfl_xor(m, off));

        const int lj4 = label >> 2, lc = label & 3;
        float s = 0.f, lv = 0.f;
#pragma unroll
        for (int k = 0; k < 4; k++) {
            int j4 = lane + k * 64;
            s += __expf(v[k].x - m) + __expf(v[k].y - m)
               + __expf(v[k].z - m) + __expf(v[k].w - m);
            float comp = (lc == 0) ? v[k].x : (lc == 1) ? v[k].y : (lc == 2) ? v[k].z : v[k].w;
            lv += (j4 == lj4) ? comp : 0.f;
        }
        for (int off = 32; off; off >>= 1) {
            s += __shfl_xor(s, off);
            lv += __shfl_xor(lv, off);
        }
        if (lane == 0) ps[w] = -(lv - m - __logf(s));
        __syncthreads();
        if (tid == 0) {
            float t = 0.f;
#pragma unroll
            for (int q = 0; q < 8; q++) t += ps[q];
            ce_part[bid] = t;
        }
    } else if (bid < 2048) {
        // ============ triplet + asq + dref + anchor->bf16, one wave per row ======
        const int i = (bid - 1536) * 8 + w;                     // [0,4096)
        const int label = la[i];
        const float4* ar = (const float4*)(a + (size_t)i * DD);
        const float4* pr = (const float4*)(p + (size_t)i * DD);
        const float4* nr = (const float4*)(n + (size_t)i * DD);
        const float4* er = (const float4*)(ex + (size_t)label * DD);
        float sa = 0.f, sp = 0.f, sn = 0.f, se = 0.f;
#pragma unroll
        for (int k = 0; k < 2; k++) {
            const int j = lane + k * 64;
            float4 av = ar[j], pv = pr[j], nv = nr[j], ev = er[j];
            union { unsigned short u[4]; uint2 q; } o;
            o.u[0]=f2bf(av.x); o.u[1]=f2bf(av.y); o.u[2]=f2bf(av.z); o.u[3]=f2bf(av.w);
            *(uint2*)(Abf + (size_t)i * DD + j * 4) = o.q;
            sa += av.x*av.x + av.y*av.y + av.z*av.z + av.w*av.w;
            float dx = av.x-pv.x, dy = av.y-pv.y, dz = av.z-pv.z, dw = av.w-pv.w;
            sp += dx*dx + dy*dy + dz*dz + dw*dw;
            dx = av.x-nv.x; dy = av.y-nv.y; dz = av.z-nv.z; dw = av.w-nv.w;
            sn += dx*dx + dy*dy + dz*dz + dw*dw;
            dx = av.x-ev.x; dy = av.y-ev.y; dz = av.z-ev.z; dw = av.w-ev.w;
            se += dx*dx + dy*dy + dz*dz + dw*dw;
        }
        for (int off = 32; off; off >>= 1) {
            sa += __shfl_xor(sa, off);
            sp += __shfl_xor(sp, off);
            sn += __shfl_xor(sn, off);
            se += __shfl_xor(se, off);
        }
        if (lane == 0) {
            asq[i]  = sa;
            dref[i] = sqrtf(se);
            pmin[i] = INFINITY;
            ps[w] = fmaxf(sqrtf(sp) - sqrtf(sn), 0.f);
        }
        __syncthreads();
        if (tid == 0) {
            float t = 0.f;
#pragma unroll
            for (int q = 0; q < 8; q++) t += ps[q];
            tr_part[bid - 1536] = t;
        }
    } else {
        // ============ exemplar->bf16 (padded) + esq, one wave per row ============
        const int c = (bid - 2048) * 8 + w;                     // [0,1024)
        float s = 0.f;
        if (c < CC) {
            const float4* row = (const float4*)(ex + (size_t)c * DD);
#pragma unroll
            for (int k = 0; k < 2; k++) {
                const int j = lane + k * 64;
                float4 v = row[j];
                union { unsigned short u[4]; uint2 q; } o;
                o.u[0]=f2bf(v.x); o.u[1]=f2bf(v.y); o.u[2]=f2bf(v.z); o.u[3]=f2bf(v.w);
                *(uint2*)(Ebf + (size_t)c * DD + j * 4) = o.q;
                s += v.x*v.x + v.y*v.y + v.z*v.z + v.w*v.w;
            }
            for (int off = 32; off; off >>= 1) s += __shfl_xor(s, off);
        } else {
            const uint2 z = make_uint2(0, 0);
#pragma unroll
            for (int k = 0; k < 2; k++) {
                const int j = lane + k * 64;
                *(uint2*)(Ebf + (size_t)c * DD + j * 4) = z;
            }
        }
        if (lane == 0) esq[c] = s;
    }
}

// ---------------------------------------------------------------------------
// K2: GEMM only. 128 blocks x 512 threads; 256x128 tile, BK=32 dbuf, counted
// vmcnt. Grid mapped so XCD (bid%8) = M-strip: per-XCD working set = 2 A-strips
// (512 KB) + full Ebf (1 MB) -> L2-resident.
// ---------------------------------------------------------------------------
#define GL2LDS(gsrc, ldst) __builtin_amdgcn_global_load_lds( \
    (const __attribute__((address_space(1))) unsigned int*)(gsrc), \
    (__attribute__((address_space(3))) unsigned int*)(ldst), 16, 0, 0)

__global__ __launch_bounds__(512) void gemm_kernel(
    const unsigned short* __restrict__ Ab, const unsigned short* __restrict__ Eb,
    const float* __restrict__ asq, const float* __restrict__ esq,
    float* __restrict__ pmin)
{
    __shared__ unsigned short lA[2][256 * 32];  // 2 x 16 KB
    __shared__ unsigned short lB[2][128 * 32];  // 2 x 8 KB
    __shared__ float s_pm[2][256];              // 2 KB

    const int bid = blockIdx.x;
    const int tid = threadIdx.x;
    const int w = tid >> 6, lane = tid & 63;

    const int wm = w >> 1, wn = w & 1;              // 4x2 waves of 64x64 tiles
    const int hi = lane >> 4, lo = lane & 15;
    const int gm0 = (bid & 15) * 256, gn0 = (bid >> 4) * 128;   // XCD = M-strip

    // staging coords: chunk c = tid covers LDS elems [8c, 8c+8):
    // row r = c>>2, group q = c&3; source K-group = q ^ ((r>>1)&3)
    const int r0 = tid >> 2, q0 = tid & 3;
    const int sw0 = q0 ^ ((r0 >> 1) & 3);           // same for r0+128
    const size_t srcA0 = ((size_t)(gm0 + r0) << 9) + (sw0 << 3);
    const size_t srcA1 = ((size_t)(gm0 + 128 + r0) << 9) + (sw0 << 3);
    const size_t srcB  = ((size_t)(gn0 + r0) << 9) + (sw0 << 3);
    const int dstA = (w << 9);                      // elems; +4096 for pass1

#define STAGE(buf, kt) do { \
    GL2LDS(Ab + srcA0 + ((kt) << 5), &lA[buf][dstA]); \
    GL2LDS(Ab + srcA1 + ((kt) << 5), &lA[buf][4096 + dstA]); \
    GL2LDS(Eb + srcB  + ((kt) << 5), &lB[buf][dstA]); \
} while (0)

    f32x4 acc[4][4];
#pragma unroll
    for (int mi = 0; mi < 4; mi++)
#pragma unroll
        for (int ni = 0; ni < 4; ni++) acc[mi][ni] = (f32x4){0.f, 0.f, 0.f, 0.f};

    STAGE(0, 0);
    for (int kt = 0; kt < 16; kt++) {
        const int buf = kt & 1;
        if (kt < 15) {
            STAGE(buf ^ 1, kt + 1);
            asm volatile("s_waitcnt vmcnt(3)" ::: "memory");
        } else {
            asm volatile("s_waitcnt vmcnt(0)" ::: "memory");
        }
        __builtin_amdgcn_s_barrier();
        asm volatile("" ::: "memory");

        short8 af[4], bf[4];
#pragma unroll
        for (int mi = 0; mi < 4; mi++) {
            int r = (wm << 6) + (mi << 4) + lo;
            af[mi] = *(const short8*)&lA[buf][(r << 5) + ((hi ^ ((r >> 1) & 3)) << 3)];
        }
#pragma unroll
        for (int ni = 0; ni < 4; ni++) {
            int r = (wn << 6) + (ni << 4) + lo;
            bf[ni] = *(const short8*)&lB[buf][(r << 5) + ((hi ^ ((r >> 1) & 3)) << 3)];
        }
#pragma unroll
        for (int mi = 0; mi < 4; mi++)
#pragma unroll
            for (int ni = 0; ni < 4; ni++)
                acc[mi][ni] = __builtin_amdgcn_mfma_f32_16x16x32_bf16(af[mi], bf[ni], acc[mi][ni], 0, 0, 0);

        asm volatile("" ::: "memory");
        __builtin_amdgcn_s_barrier();
    }
#undef STAGE

    // ---- epilogue: d = sqrt(asq + esq - 2 dot); col-min over 128 cols ----
    // C/D: col = lane&15, row = (lane>>4)*4 + j  [m89-verified]
    float aq[4][4];
#pragma unroll
    for (int mi = 0; mi < 4; mi++) {
        float4 a0 = *(const float4*)&asq[gm0 + wm * 64 + mi * 16 + hi * 4];
        aq[mi][0]=a0.x; aq[mi][1]=a0.y; aq[mi][2]=a0.z; aq[mi][3]=a0.w;
    }
    float esqc[4]; int bad[4];
#pragma unroll
    for (int ni = 0; ni < 4; ni++) {
        int gn = gn0 + wn * 64 + ni * 16 + lo;
        esqc[ni] = esq[gn];
        bad[ni] = (gn >= CC);
    }
    float vmin[4][4];
#pragma unroll
    for (int mi = 0; mi < 4; mi++)
#pragma unroll
        for (int j = 0; j < 4; j++) {
            float best = INFINITY;
#pragma unroll
            for (int ni = 0; ni < 4; ni++) {
                float d2 = aq[mi][j] + esqc[ni] - 2.f * acc[mi][ni][j];
                float d = sqrtf(fmaxf(d2, 0.f));
                if (bad[ni]) d = INFINITY;
                best = fminf(best, d);
            }
            vmin[mi][j] = best;
        }
#pragma unroll
    for (int off = 1; off < 16; off <<= 1)
#pragma unroll
        for (int mi = 0; mi < 4; mi++)
#pragma unroll
            for (int j = 0; j < 4; j++)
                vmin[mi][j] = fminf(vmin[mi][j], __shfl_xor(vmin[mi][j], off));

    if (lo == 0) {
#pragma unroll
        for (int mi = 0; mi < 4; mi++)
#pragma unroll
            for (int j = 0; j < 4; j++)
                s_pm[wn][wm * 64 + mi * 16 + hi * 4 + j] = vmin[mi][j];
    }
    __syncthreads();
    if (tid < 256) {
        float m2 = fminf(s_pm[0][tid], s_pm[1][tid]);
        // d >= 0 -> float order == int order; min is order-independent.
        atomicMin((int*)pmin + gm0 + tid, __float_as_int(m2));
    }
}

// ---------------------------------------------------------------------------
// final: reduce partials; center loss from pmin + dref; combine.
// ---------------------------------------------------------------------------
__global__ __launch_bounds__(1024) void final_kernel(
    const float* __restrict__ ce_part, const float* __restrict__ tr_part,
    const float* __restrict__ pmin, const float* __restrict__ dref,
    float* __restrict__ out)
{
    int tid = threadIdx.x;
    float ce = 0.f, tr = (tid < 512) ? tr_part[tid] : 0.f, ctr = 0.f;
    if (tid < 1536) ce = ce_part[tid] + ((tid < 512) ? ce_part[tid + 1024] : 0.f);
#pragma unroll
    for (int a = 0; a < 4; a++) {
        int m = a * 1024 + tid;
        ctr += fmaxf(dref[m] - pmin[m], 0.f);
    }
    for (int off = 32; off; off >>= 1) {
        ce += __shfl_xor(ce, off);
        tr += __shfl_xor(tr, off);
        ctr += __shfl_xor(ctr, off);
    }
    __shared__ float s[3][16];
    int wid = tid >> 6, lane = tid & 63;
    if (lane == 0) { s[0][wid] = ce; s[1][wid] = tr; s[2][wid] = ctr; }
    __syncthreads();
    if (tid == 0) {
        float tce = 0.f, ttr = 0.f, tctr = 0.f;
#pragma unroll
        for (int w = 0; w < 16; w++) { tce += s[0][w]; ttr += s[1][w]; tctr += s[2][w]; }
        float lsm = tce / (3.f * BB);
        out[0] = lsm + 0.1f * tctr + 1.0f * ttr;
        out[1] = ttr;
        out[2] = lsm;
        out[3] = tctr;
    }
}

extern "C" void kernel_launch(void* const* d_in, const int* in_sizes, int n_in,
                              void* d_out, int out_size, void* d_ws, size_t ws_size,
                              hipStream_t stream) {
    const float* anchor   = (const float*)d_in[0];
    const float* positive = (const float*)d_in[1];
    const float* negative = (const float*)d_in[2];
    const float* outputs  = (const float*)d_in[3];
    const int*   la       = (const int*)d_in[4];
    const int*   ln       = (const int*)d_in[5];
    const float* ex       = (const float*)d_in[6];
    float* out = (float*)d_out;
    float* ws  = (float*)d_ws;

    unsigned short* Abf = (unsigned short*)(ws + OFF_ABF);
    unsigned short* Ebf = (unsigned short*)(ws + OFF_EBF);
    float* esq      = ws + OFF_ESQ;
    float* asq      = ws + OFF_ASQ;
    float* dref     = ws + OFF_DREF;
    float* pmin     = ws + OFF_PMIN;
    float* ce_part  = ws + OFF_CEP;
    float* tr_part  = ws + OFF_TRP;

    hipLaunchKernelGGL(k1_kernel,    dim3(2176), dim3(512),  0, stream,
                       anchor, positive, negative, ex, outputs, la, ln,
                       Abf, Ebf, esq, asq, dref, tr_part, pmin, ce_part);
    hipLaunchKernelGGL(gemm_kernel,  dim3(128),  dim3(512),  0, stream,
                       Abf, Ebf, asq, esq, pmin);
    hipLaunchKernelGGL(final_kernel, dim3(1),    dim3(1024), 0, stream,
                       ce_part, tr_part, pmin, dref, out);
}

// Round 9
// 34.217 us; speedup vs baseline: 1.1129x; 1.1129x over previous
//
#include <hip/hip_runtime.h>
#include <math.h>

// Problem constants
#define BB 4096      // batch
#define DD 512       // feature dim
#define CC 1000      // num classes

typedef __attribute__((ext_vector_type(8))) short short8;
typedef __attribute__((ext_vector_type(4))) float f32x4;

// ---------------- ws layout (float slots) ----------------
#define OFF_ABF  0              // 4096x512 bf16 = 1048576 float slots
#define OFF_EBF  1048576        // 1024x512 bf16 = 262144
#define OFF_ESQ  1310720        // 1024
#define OFF_ASQ  1311744        // 4096
#define OFF_DREF 1315840        // 4096
#define OFF_PMIN 1319936        // 4096
#define OFF_CEP  1324032        // 1536
#define OFF_TRP  1327104        // 512

__device__ __forceinline__ unsigned short f2bf(float x) {
    unsigned u = __float_as_uint(x);
    unsigned r = (u + 0x7FFFu + ((u >> 16) & 1u)) >> 16;   // RNE
    return (unsigned short)r;
}

// ---------------------------------------------------------------------------
// prep: 640 blocks x 512 threads.
//   bid < 512        : triplet + asq + exact dref + anchor->bf16 + pmin=INF (8 rows/blk)
//   512 <= bid < 640 : exemplar->bf16 (padded) + esq (8 rows/blk)
// ---------------------------------------------------------------------------
__global__ __launch_bounds__(512) void prep_kernel(
    const float* __restrict__ a, const float* __restrict__ p,
    const float* __restrict__ n, const float* __restrict__ ex,
    const int* __restrict__ la,
    unsigned short* __restrict__ Abf, unsigned short* __restrict__ Ebf,
    float* __restrict__ esq, float* __restrict__ asq,
    float* __restrict__ dref, float* __restrict__ tr_part,
    float* __restrict__ pmin)
{
    __shared__ float ps[8];
    const int bid = blockIdx.x;
    const int tid = threadIdx.x;
    const int w = tid >> 6, lane = tid & 63;

    if (bid < 512) {
        const int i = bid * 8 + w;                      // [0,4096)
        const int label = la[i];
        const float4* ar = (const float4*)(a + (size_t)i * DD);
        const float4* pr = (const float4*)(p + (size_t)i * DD);
        const float4* nr = (const float4*)(n + (size_t)i * DD);
        const float4* er = (const float4*)(ex + (size_t)label * DD);
        float sa = 0.f, sp = 0.f, sn = 0.f, se = 0.f;
#pragma unroll
        for (int k = 0; k < 2; k++) {
            const int j = lane + k * 64;
            float4 av = ar[j], pv = pr[j], nv = nr[j], ev = er[j];
            union { unsigned short u[4]; uint2 q; } o;
            o.u[0]=f2bf(av.x); o.u[1]=f2bf(av.y); o.u[2]=f2bf(av.z); o.u[3]=f2bf(av.w);
            *(uint2*)(Abf + (size_t)i * DD + j * 4) = o.q;
            sa += av.x*av.x + av.y*av.y + av.z*av.z + av.w*av.w;
            float dx = av.x-pv.x, dy = av.y-pv.y, dz = av.z-pv.z, dw = av.w-pv.w;
            sp += dx*dx + dy*dy + dz*dz + dw*dw;
            dx = av.x-nv.x; dy = av.y-nv.y; dz = av.z-nv.z; dw = av.w-nv.w;
            sn += dx*dx + dy*dy + dz*dz + dw*dw;
            dx = av.x-ev.x; dy = av.y-ev.y; dz = av.z-ev.z; dw = av.w-ev.w;
            se += dx*dx + dy*dy + dz*dz + dw*dw;
        }
        for (int off = 32; off; off >>= 1) {
            sa += __shfl_xor(sa, off);
            sp += __shfl_xor(sp, off);
            sn += __shfl_xor(sn, off);
            se += __shfl_xor(se, off);
        }
        if (lane == 0) {
            asq[i]  = sa;
            dref[i] = sqrtf(se);
            pmin[i] = INFINITY;
            ps[w] = fmaxf(sqrtf(sp) - sqrtf(sn), 0.f);
        }
        __syncthreads();
        if (tid == 0) {
            float t = 0.f;
#pragma unroll
            for (int q = 0; q < 8; q++) t += ps[q];
            tr_part[bid] = t;
        }
    } else {
        const int c = (bid - 512) * 8 + w;              // [0,1024)
        float s = 0.f;
        if (c < CC) {
            const float4* row = (const float4*)(ex + (size_t)c * DD);
#pragma unroll
            for (int k = 0; k < 2; k++) {
                const int j = lane + k * 64;
                float4 v = row[j];
                union { unsigned short u[4]; uint2 q; } o;
                o.u[0]=f2bf(v.x); o.u[1]=f2bf(v.y); o.u[2]=f2bf(v.z); o.u[3]=f2bf(v.w);
                *(uint2*)(Ebf + (size_t)c * DD + j * 4) = o.q;
                s += v.x*v.x + v.y*v.y + v.z*v.z + v.w*v.w;
            }
            for (int off = 32; off; off >>= 1) s += __shfl_xor(s, off);
        } else {
            const uint2 z = make_uint2(0, 0);
#pragma unroll
            for (int k = 0; k < 2; k++) {
                const int j = lane + k * 64;
                *(uint2*)(Ebf + (size_t)c * DD + j * 4) = z;
            }
        }
        if (lane == 0) esq[c] = s;
    }
}

// ---------------------------------------------------------------------------
// main: 1664 blocks x 512 threads, fused roles (m114 co-scheduling).
//   bid < 128  -> GEMM 256x128 tile, BK=64 single-buffer (m97 inner pattern),
//                 XCD = M-strip (bid&15 -> strips {x,x+8} per XCD, L2-resident)
//   bid >= 128 -> CE, 8 rows/block (keeps CUs busy over GEMM's vmcnt drains)
// ---------------------------------------------------------------------------
#define GL2LDS(gsrc, ldst) __builtin_amdgcn_global_load_lds( \
    (const __attribute__((address_space(1))) unsigned int*)(gsrc), \
    (__attribute__((address_space(3))) unsigned int*)(ldst), 16, 0, 0)

__global__ __launch_bounds__(512) void main_kernel(
    const unsigned short* __restrict__ Ab, const unsigned short* __restrict__ Eb,
    const float* __restrict__ asq, const float* __restrict__ esq,
    const float* __restrict__ outp,
    const int* __restrict__ la, const int* __restrict__ ln,
    float* __restrict__ pmin, float* __restrict__ ce_part)
{
    __shared__ unsigned short lA[256 * 64];     // 32 KB
    __shared__ unsigned short lB[128 * 64];     // 16 KB
    __shared__ float s_pm[2][256];              // 2 KB
    __shared__ float ps[8];

    const int bid = blockIdx.x;
    const int tid = threadIdx.x;
    const int w = tid >> 6, lane = tid & 63;

    if (bid < 128) {
        // ============ GEMM 256x128, BK=64 single-buffer ============
        const int wm = w >> 1, wn = w & 1;              // 4x2 waves of 64x64 tiles
        const int hi = lane >> 4, lo = lane & 15;
        const int gm0 = (bid & 15) * 256, gn0 = (bid >> 4) * 128;   // XCD = M-strip

        // staging: chunk c (16B) -> LDS row r=c>>3 slot s=c&7; src k-group = s^(r&7)
        size_t srcA[4], srcB[2]; int dstA[4], dstB[2];
#pragma unroll
        for (int i = 0; i < 4; i++) {
            int c = tid + i * 512, r = c >> 3, s = c & 7;
            srcA[i] = ((size_t)(gm0 + r) << 9) + ((s ^ (r & 7)) << 3);
            dstA[i] = c << 3;
        }
#pragma unroll
        for (int i = 0; i < 2; i++) {
            int c = tid + i * 512, r = c >> 3, s = c & 7;
            srcB[i] = ((size_t)(gn0 + r) << 9) + ((s ^ (r & 7)) << 3);
            dstB[i] = c << 3;
        }

        f32x4 acc[4][4];
#pragma unroll
        for (int mi = 0; mi < 4; mi++)
#pragma unroll
            for (int ni = 0; ni < 4; ni++) acc[mi][ni] = (f32x4){0.f, 0.f, 0.f, 0.f};

        for (int kt = 0; kt < 8; kt++) {
#pragma unroll
            for (int i = 0; i < 4; i++) GL2LDS(Ab + srcA[i] + (kt << 6), &lA[dstA[i]]);
#pragma unroll
            for (int i = 0; i < 2; i++) GL2LDS(Eb + srcB[i] + (kt << 6), &lB[dstB[i]]);
            asm volatile("s_waitcnt vmcnt(0)" ::: "memory");
            __builtin_amdgcn_s_barrier();
            asm volatile("" ::: "memory");

#pragma unroll
            for (int kk = 0; kk < 2; kk++) {
                short8 af[4], bf[4];
#pragma unroll
                for (int mi = 0; mi < 4; mi++) {
                    int r = (wm << 6) + (mi << 4) + lo, s = (kk << 2) + hi;
                    af[mi] = *(const short8*)&lA[(r << 6) + ((s ^ (r & 7)) << 3)];
                }
#pragma unroll
                for (int ni = 0; ni < 4; ni++) {
                    int r = (wn << 6) + (ni << 4) + lo, s = (kk << 2) + hi;
                    bf[ni] = *(const short8*)&lB[(r << 6) + ((s ^ (r & 7)) << 3)];
                }
#pragma unroll
                for (int mi = 0; mi < 4; mi++)
#pragma unroll
                    for (int ni = 0; ni < 4; ni++)
                        acc[mi][ni] = __builtin_amdgcn_mfma_f32_16x16x32_bf16(af[mi], bf[ni], acc[mi][ni], 0, 0, 0);
            }
            asm volatile("" ::: "memory");
            __builtin_amdgcn_s_barrier();
        }

        // ---- epilogue: d = sqrt(asq + esq - 2 dot); col-min over 128 cols ----
        // C/D: col = lane&15, row = (lane>>4)*4 + j  [m89-verified]
        float aq[4][4];
#pragma unroll
        for (int mi = 0; mi < 4; mi++) {
            float4 a0 = *(const float4*)&asq[gm0 + wm * 64 + mi * 16 + hi * 4];
            aq[mi][0]=a0.x; aq[mi][1]=a0.y; aq[mi][2]=a0.z; aq[mi][3]=a0.w;
        }
        float esqc[4]; int bad[4];
#pragma unroll
        for (int ni = 0; ni < 4; ni++) {
            int gn = gn0 + wn * 64 + ni * 16 + lo;
            esqc[ni] = esq[gn];
            bad[ni] = (gn >= CC);
        }
        float vmin[4][4];
#pragma unroll
        for (int mi = 0; mi < 4; mi++)
#pragma unroll
            for (int j = 0; j < 4; j++) {
                float best = INFINITY;
#pragma unroll
                for (int ni = 0; ni < 4; ni++) {
                    float d2 = aq[mi][j] + esqc[ni] - 2.f * acc[mi][ni][j];
                    float d = sqrtf(fmaxf(d2, 0.f));
                    if (bad[ni]) d = INFINITY;
                    best = fminf(best, d);
                }
                vmin[mi][j] = best;
            }
#pragma unroll
        for (int off = 1; off < 16; off <<= 1)
#pragma unroll
            for (int mi = 0; mi < 4; mi++)
#pragma unroll
                for (int j = 0; j < 4; j++)
                    vmin[mi][j] = fminf(vmin[mi][j], __shfl_xor(vmin[mi][j], off));

        if (lo == 0) {
#pragma unroll
            for (int mi = 0; mi < 4; mi++)
#pragma unroll
                for (int j = 0; j < 4; j++)
                    s_pm[wn][wm * 64 + mi * 16 + hi * 4 + j] = vmin[mi][j];
        }
        __syncthreads();
        if (tid < 256) {
            float m2 = fminf(s_pm[0][tid], s_pm[1][tid]);
            // d >= 0 -> float order == int order; min is order-independent.
            atomicMin((int*)pmin + gm0 + tid, __float_as_int(m2));
        }
    } else {
        // =================== CE: one wave per row, float4 loads ===================
        const int cb = bid - 128;                               // [0,1536)
        const int r = cb * 8 + w;                               // [0,12288)
        const int label = (r < 2 * BB) ? la[r & (BB - 1)] : ln[r - 2 * BB];
        const float4* row4 = (const float4*)(outp + (size_t)r * CC);   // 250 float4
        float4 v[4];
#pragma unroll
        for (int k = 0; k < 4; k++) {
            int j4 = lane + k * 64;
            v[k] = (j4 < 250) ? row4[j4]
                              : make_float4(-INFINITY, -INFINITY, -INFINITY, -INFINITY);
        }
        float m = -INFINITY;
#pragma unroll
        for (int k = 0; k < 4; k++)
            m = fmaxf(m, fmaxf(fmaxf(v[k].x, v[k].y), fmaxf(v[k].z, v[k].w)));
        for (int off = 32; off; off >>= 1) m = fmaxf(m, __shfl_xor(m, off));

        const int lj4 = label >> 2, lc = label & 3;
        float s = 0.f, lv = 0.f;
#pragma unroll
        for (int k = 0; k < 4; k++) {
            int j4 = lane + k * 64;
            s += __expf(v[k].x - m) + __expf(v[k].y - m)
               + __expf(v[k].z - m) + __expf(v[k].w - m);
            float comp = (lc == 0) ? v[k].x : (lc == 1) ? v[k].y : (lc == 2) ? v[k].z : v[k].w;
            lv += (j4 == lj4) ? comp : 0.f;
        }
        for (int off = 32; off; off >>= 1) {
            s += __shfl_xor(s, off);
            lv += __shfl_xor(lv, off);
        }
        if (lane == 0) ps[w] = -(lv - m - __logf(s));
        __syncthreads();
        if (tid == 0) {
            float t = 0.f;
#pragma unroll
            for (int q = 0; q < 8; q++) t += ps[q];
            ce_part[cb] = t;
        }
    }
}

// ---------------------------------------------------------------------------
// final: reduce partials; center loss from pmin + dref; combine.
// ---------------------------------------------------------------------------
__global__ __launch_bounds__(1024) void final_kernel(
    const float* __restrict__ ce_part, const float* __restrict__ tr_part,
    const float* __restrict__ pmin, const float* __restrict__ dref,
    float* __restrict__ out)
{
    int tid = threadIdx.x;
    float ce = 0.f, tr = (tid < 512) ? tr_part[tid] : 0.f, ctr = 0.f;
    if (tid < 1536) ce = ce_part[tid] + ((tid < 512) ? ce_part[tid + 1024] : 0.f);
#pragma unroll
    for (int a = 0; a < 4; a++) {
        int m = a * 1024 + tid;
        ctr += fmaxf(dref[m] - pmin[m], 0.f);
    }
    for (int off = 32; off; off >>= 1) {
        ce += __shfl_xor(ce, off);
        tr += __shfl_xor(tr, off);
        ctr += __shfl_xor(ctr, off);
    }
    __shared__ float s[3][16];
    int wid = tid >> 6, lane = tid & 63;
    if (lane == 0) { s[0][wid] = ce; s[1][wid] = tr; s[2][wid] = ctr; }
    __syncthreads();
    if (tid == 0) {
        float tce = 0.f, ttr = 0.f, tctr = 0.f;
#pragma unroll
        for (int w = 0; w < 16; w++) { tce += s[0][w]; ttr += s[1][w]; tctr += s[2][w]; }
        float lsm = tce / (3.f * BB);
        out[0] = lsm + 0.1f * tctr + 1.0f * ttr;
        out[1] = ttr;
        out[2] = lsm;
        out[3] = tctr;
    }
}

extern "C" void kernel_launch(void* const* d_in, const int* in_sizes, int n_in,
                              void* d_out, int out_size, void* d_ws, size_t ws_size,
                              hipStream_t stream) {
    const float* anchor   = (const float*)d_in[0];
    const float* positive = (const float*)d_in[1];
    const float* negative = (const float*)d_in[2];
    const float* outputs  = (const float*)d_in[3];
    const int*   la       = (const int*)d_in[4];
    const int*   ln       = (const int*)d_in[5];
    const float* ex       = (const float*)d_in[6];
    float* out = (float*)d_out;
    float* ws  = (float*)d_ws;

    unsigned short* Abf = (unsigned short*)(ws + OFF_ABF);
    unsigned short* Ebf = (unsigned short*)(ws + OFF_EBF);
    float* esq      = ws + OFF_ESQ;
    float* asq      = ws + OFF_ASQ;
    float* dref     = ws + OFF_DREF;
    float* pmin     = ws + OFF_PMIN;
    float* ce_part  = ws + OFF_CEP;
    float* tr_part  = ws + OFF_TRP;

    hipLaunchKernelGGL(prep_kernel,  dim3(640),  dim3(512),  0, stream,
                       anchor, positive, negative, ex, la, Abf, Ebf, esq, asq, dref, tr_part, pmin);
    hipLaunchKernelGGL(main_kernel,  dim3(1664), dim3(512),  0, stream,
                       Abf, Ebf, asq, esq, outputs, la, ln, pmin, ce_part);
    hipLaunchKernelGGL(final_kernel, dim3(1),    dim3(1024), 0, stream,
                       ce_part, tr_part, pmin, dref, out);
}

// Round 10
// 31.385 us; speedup vs baseline: 1.2134x; 1.0902x over previous
//
#include <hip/hip_runtime.h>
#include <math.h>

// Problem constants
#define BB 4096      // batch
#define DD 512       // feature dim
#define CC 1000      // num classes

typedef __attribute__((ext_vector_type(8))) short short8;
typedef __attribute__((ext_vector_type(4))) float f32x4;

// ---------------- ws layout (float slots) ----------------
#define OFF_ABF  0              // 4096x512 bf16 = 1048576 float slots
#define OFF_EBF  1048576        // 1024x512 bf16 = 262144
#define OFF_ESQ  1310720        // 1024
#define OFF_ASQ  1311744        // 4096
#define OFF_DREF 1315840        // 4096
#define OFF_PMIN 1319936        // 4096
#define OFF_CEP  1324032        // 1536
#define OFF_TRP  1327104        // 512

__device__ __forceinline__ unsigned short f2bf(float x) {
    unsigned u = __float_as_uint(x);
    unsigned r = (u + 0x7FFFu + ((u >> 16) & 1u)) >> 16;   // RNE
    return (unsigned short)r;
}

// ---------------------------------------------------------------------------
// prep: 640 blocks x 512 threads.
//   bid < 512        : triplet + asq + exact dref + anchor->bf16 + pmin=INF (8 rows/blk)
//   512 <= bid < 640 : exemplar->bf16 (padded) + esq (8 rows/blk)
// ---------------------------------------------------------------------------
__global__ __launch_bounds__(512) void prep_kernel(
    const float* __restrict__ a, const float* __restrict__ p,
    const float* __restrict__ n, const float* __restrict__ ex,
    const int* __restrict__ la,
    unsigned short* __restrict__ Abf, unsigned short* __restrict__ Ebf,
    float* __restrict__ esq, float* __restrict__ asq,
    float* __restrict__ dref, float* __restrict__ tr_part,
    float* __restrict__ pmin)
{
    __shared__ float ps[8];
    const int bid = blockIdx.x;
    const int tid = threadIdx.x;
    const int w = tid >> 6, lane = tid & 63;

    if (bid < 512) {
        const int i = bid * 8 + w;                      // [0,4096)
        const int label = la[i];
        const float4* ar = (const float4*)(a + (size_t)i * DD);
        const float4* pr = (const float4*)(p + (size_t)i * DD);
        const float4* nr = (const float4*)(n + (size_t)i * DD);
        const float4* er = (const float4*)(ex + (size_t)label * DD);
        float sa = 0.f, sp = 0.f, sn = 0.f, se = 0.f;
#pragma unroll
        for (int k = 0; k < 2; k++) {
            const int j = lane + k * 64;
            float4 av = ar[j], pv = pr[j], nv = nr[j], ev = er[j];
            union { unsigned short u[4]; uint2 q; } o;
            o.u[0]=f2bf(av.x); o.u[1]=f2bf(av.y); o.u[2]=f2bf(av.z); o.u[3]=f2bf(av.w);
            *(uint2*)(Abf + (size_t)i * DD + j * 4) = o.q;
            sa += av.x*av.x + av.y*av.y + av.z*av.z + av.w*av.w;
            float dx = av.x-pv.x, dy = av.y-pv.y, dz = av.z-pv.z, dw = av.w-pv.w;
            sp += dx*dx + dy*dy + dz*dz + dw*dw;
            dx = av.x-nv.x; dy = av.y-nv.y; dz = av.z-nv.z; dw = av.w-nv.w;
            sn += dx*dx + dy*dy + dz*dz + dw*dw;
            dx = av.x-ev.x; dy = av.y-ev.y; dz = av.z-ev.z; dw = av.w-ev.w;
            se += dx*dx + dy*dy + dz*dz + dw*dw;
        }
        for (int off = 32; off; off >>= 1) {
            sa += __shfl_xor(sa, off);
            sp += __shfl_xor(sp, off);
            sn += __shfl_xor(sn, off);
            se += __shfl_xor(se, off);
        }
        if (lane == 0) {
            asq[i]  = sa;
            dref[i] = sqrtf(se);
            pmin[i] = INFINITY;
            ps[w] = fmaxf(sqrtf(sp) - sqrtf(sn), 0.f);
        }
        __syncthreads();
        if (tid == 0) {
            float t = 0.f;
#pragma unroll
            for (int q = 0; q < 8; q++) t += ps[q];
            tr_part[bid] = t;
        }
    } else {
        const int c = (bid - 512) * 8 + w;              // [0,1024)
        float s = 0.f;
        if (c < CC) {
            const float4* row = (const float4*)(ex + (size_t)c * DD);
#pragma unroll
            for (int k = 0; k < 2; k++) {
                const int j = lane + k * 64;
                float4 v = row[j];
                union { unsigned short u[4]; uint2 q; } o;
                o.u[0]=f2bf(v.x); o.u[1]=f2bf(v.y); o.u[2]=f2bf(v.z); o.u[3]=f2bf(v.w);
                *(uint2*)(Ebf + (size_t)c * DD + j * 4) = o.q;
                s += v.x*v.x + v.y*v.y + v.z*v.z + v.w*v.w;
            }
            for (int off = 32; off; off >>= 1) s += __shfl_xor(s, off);
        } else {
            const uint2 z = make_uint2(0, 0);
#pragma unroll
            for (int k = 0; k < 2; k++) {
                const int j = lane + k * 64;
                *(uint2*)(Ebf + (size_t)c * DD + j * 4) = z;
            }
        }
        if (lane == 0) esq[c] = s;
    }
}

// ---------------------------------------------------------------------------
// main: 1792 blocks x 512 threads, fused roles (m114 co-scheduling).
//   bid < 256  -> GEMM 128x128 tile, BK=64 single-buffer; strip = bid&31
//                 (XCD = strip%8: 4 A-strips + full Ebf L2-resident per XCD)
//   bid >= 256 -> CE, 8 rows/block
// LDS ~34 KB -> 4 blocks/CU (full 32-wave occupancy for CE role).
// ---------------------------------------------------------------------------
#define GL2LDS(gsrc, ldst) __builtin_amdgcn_global_load_lds( \
    (const __attribute__((address_space(1))) unsigned int*)(gsrc), \
    (__attribute__((address_space(3))) unsigned int*)(ldst), 16, 0, 0)

__global__ __launch_bounds__(512) void main_kernel(
    const unsigned short* __restrict__ Ab, const unsigned short* __restrict__ Eb,
    const float* __restrict__ asq, const float* __restrict__ esq,
    const float* __restrict__ outp,
    const int* __restrict__ la, const int* __restrict__ ln,
    float* __restrict__ pmin, float* __restrict__ ce_part)
{
    __shared__ unsigned short lA[128 * 64];     // 16 KB
    __shared__ unsigned short lB[128 * 64];     // 16 KB
    __shared__ float s_pm[4][128];              // 2 KB
    __shared__ float ps[8];

    const int bid = blockIdx.x;
    const int tid = threadIdx.x;
    const int w = tid >> 6, lane = tid & 63;

    if (bid < 256) {
        // ============ GEMM 128x128, BK=64 single-buffer ============
        const int strip = bid & 31, panel = bid >> 5;   // XCD = strip%8
        const int gm0 = strip * 128, gn0 = panel * 128;
        const int wm = w >> 2, wn = w & 3;              // 2x4 waves of 64x32 tiles
        const int hi = lane >> 4, lo = lane & 15;

        // staging: chunk c (16B) -> LDS row r=c>>3 slot s=c&7; src k-group = s^(r&7)
        size_t srcA[2], srcB[2]; int dst2[2];
#pragma unroll
        for (int i = 0; i < 2; i++) {
            int c = tid + i * 512, r = c >> 3, s = c & 7;
            srcA[i] = ((size_t)(gm0 + r) << 9) + ((s ^ (r & 7)) << 3);
            srcB[i] = ((size_t)(gn0 + r) << 9) + ((s ^ (r & 7)) << 3);
            dst2[i] = c << 3;
        }

        f32x4 acc[4][2];
#pragma unroll
        for (int mi = 0; mi < 4; mi++)
#pragma unroll
            for (int ni = 0; ni < 2; ni++) acc[mi][ni] = (f32x4){0.f, 0.f, 0.f, 0.f};

        for (int kt = 0; kt < 8; kt++) {
#pragma unroll
            for (int i = 0; i < 2; i++) {
                GL2LDS(Ab + srcA[i] + (kt << 6), &lA[dst2[i]]);
                GL2LDS(Eb + srcB[i] + (kt << 6), &lB[dst2[i]]);
            }
            asm volatile("s_waitcnt vmcnt(0)" ::: "memory");
            __builtin_amdgcn_s_barrier();
            asm volatile("" ::: "memory");

#pragma unroll
            for (int kk = 0; kk < 2; kk++) {
                short8 af[4], bf[2];
#pragma unroll
                for (int mi = 0; mi < 4; mi++) {
                    int r = (wm << 6) + (mi << 4) + lo, s = (kk << 2) + hi;
                    af[mi] = *(const short8*)&lA[(r << 6) + ((s ^ (r & 7)) << 3)];
                }
#pragma unroll
                for (int ni = 0; ni < 2; ni++) {
                    int r = (wn << 5) + (ni << 4) + lo, s = (kk << 2) + hi;
                    bf[ni] = *(const short8*)&lB[(r << 6) + ((s ^ (r & 7)) << 3)];
                }
#pragma unroll
                for (int mi = 0; mi < 4; mi++)
#pragma unroll
                    for (int ni = 0; ni < 2; ni++)
                        acc[mi][ni] = __builtin_amdgcn_mfma_f32_16x16x32_bf16(af[mi], bf[ni], acc[mi][ni], 0, 0, 0);
            }
            asm volatile("" ::: "memory");
            __builtin_amdgcn_s_barrier();
        }

        // ---- epilogue: d = sqrt(asq + esq - 2 dot); col-min over 128 cols ----
        // C/D: col = lane&15, row = (lane>>4)*4 + j  [m89-verified]
        float aq[4][4];
#pragma unroll
        for (int mi = 0; mi < 4; mi++) {
            float4 a0 = *(const float4*)&asq[gm0 + wm * 64 + mi * 16 + hi * 4];
            aq[mi][0]=a0.x; aq[mi][1]=a0.y; aq[mi][2]=a0.z; aq[mi][3]=a0.w;
        }
        float esqc[2]; int bad[2];
#pragma unroll
        for (int ni = 0; ni < 2; ni++) {
            int gn = gn0 + wn * 32 + ni * 16 + lo;
            esqc[ni] = esq[gn];
            bad[ni] = (gn >= CC);
        }
        float vmin[4][4];
#pragma unroll
        for (int mi = 0; mi < 4; mi++)
#pragma unroll
            for (int j = 0; j < 4; j++) {
                float best = INFINITY;
#pragma unroll
                for (int ni = 0; ni < 2; ni++) {
                    float d2 = aq[mi][j] + esqc[ni] - 2.f * acc[mi][ni][j];
                    float d = sqrtf(fmaxf(d2, 0.f));
                    if (bad[ni]) d = INFINITY;
                    best = fminf(best, d);
                }
                vmin[mi][j] = best;
            }
#pragma unroll
        for (int off = 1; off < 16; off <<= 1)
#pragma unroll
            for (int mi = 0; mi < 4; mi++)
#pragma unroll
                for (int j = 0; j < 4; j++)
                    vmin[mi][j] = fminf(vmin[mi][j], __shfl_xor(vmin[mi][j], off));

        if (lo == 0) {
#pragma unroll
            for (int mi = 0; mi < 4; mi++)
#pragma unroll
                for (int j = 0; j < 4; j++)
                    s_pm[wn][wm * 64 + mi * 16 + hi * 4 + j] = vmin[mi][j];
        }
        __syncthreads();
        if (tid < 128) {
            float m2 = fminf(fminf(s_pm[0][tid], s_pm[1][tid]),
                             fminf(s_pm[2][tid], s_pm[3][tid]));
            // d >= 0 -> float order == int order; min is order-independent.
            atomicMin((int*)pmin + gm0 + tid, __float_as_int(m2));
        }
    } else {
        // =================== CE: one wave per row, float4 loads ===================
        const int cb = bid - 256;                               // [0,1536)
        const int r = cb * 8 + w;                               // [0,12288)
        const int label = (r < 2 * BB) ? la[r & (BB - 1)] : ln[r - 2 * BB];
        const float4* row4 = (const float4*)(outp + (size_t)r * CC);   // 250 float4
        float4 v[4];
#pragma unroll
        for (int k = 0; k < 4; k++) {
            int j4 = lane + k * 64;
            v[k] = (j4 < 250) ? row4[j4]
                              : make_float4(-INFINITY, -INFINITY, -INFINITY, -INFINITY);
        }
        float m = -INFINITY;
#pragma unroll
        for (int k = 0; k < 4; k++)
            m = fmaxf(m, fmaxf(fmaxf(v[k].x, v[k].y), fmaxf(v[k].z, v[k].w)));
        for (int off = 32; off; off >>= 1) m = fmaxf(m, __shfl_xor(m, off));

        const int lj4 = label >> 2, lc = label & 3;
        float s = 0.f, lv = 0.f;
#pragma unroll
        for (int k = 0; k < 4; k++) {
            int j4 = lane + k * 64;
            s += __expf(v[k].x - m) + __expf(v[k].y - m)
               + __expf(v[k].z - m) + __expf(v[k].w - m);
            float comp = (lc == 0) ? v[k].x : (lc == 1) ? v[k].y : (lc == 2) ? v[k].z : v[k].w;
            lv += (j4 == lj4) ? comp : 0.f;
        }
        for (int off = 32; off; off >>= 1) {
            s += __shfl_xor(s, off);
            lv += __shfl_xor(lv, off);
        }
        if (lane == 0) ps[w] = -(lv - m - __logf(s));
        __syncthreads();
        if (tid == 0) {
            float t = 0.f;
#pragma unroll
            for (int q = 0; q < 8; q++) t += ps[q];
            ce_part[cb] = t;
        }
    }
}

// ---------------------------------------------------------------------------
// final: reduce partials; center loss from pmin + dref; combine.
// ---------------------------------------------------------------------------
__global__ __launch_bounds__(1024) void final_kernel(
    const float* __restrict__ ce_part, const float* __restrict__ tr_part,
    const float* __restrict__ pmin, const float* __restrict__ dref,
    float* __restrict__ out)
{
    int tid = threadIdx.x;
    float ce = 0.f, tr = (tid < 512) ? tr_part[tid] : 0.f, ctr = 0.f;
    if (tid < 1536) ce = ce_part[tid] + ((tid < 512) ? ce_part[tid + 1024] : 0.f);
#pragma unroll
    for (int a = 0; a < 4; a++) {
        int m = a * 1024 + tid;
        ctr += fmaxf(dref[m] - pmin[m], 0.f);
    }
    for (int off = 32; off; off >>= 1) {
        ce += __shfl_xor(ce, off);
        tr += __shfl_xor(tr, off);
        ctr += __shfl_xor(ctr, off);
    }
    __shared__ float s[3][16];
    int wid = tid >> 6, lane = tid & 63;
    if (lane == 0) { s[0][wid] = ce; s[1][wid] = tr; s[2][wid] = ctr; }
    __syncthreads();
    if (tid == 0) {
        float tce = 0.f, ttr = 0.f, tctr = 0.f;
#pragma unroll
        for (int w = 0; w < 16; w++) { tce += s[0][w]; ttr += s[1][w]; tctr += s[2][w]; }
        float lsm = tce / (3.f * BB);
        out[0] = lsm + 0.1f * tctr + 1.0f * ttr;
        out[1] = ttr;
        out[2] = lsm;
        out[3] = tctr;
    }
}

extern "C" void kernel_launch(void* const* d_in, const int* in_sizes, int n_in,
                              void* d_out, int out_size, void* d_ws, size_t ws_size,
                              hipStream_t stream) {
    const float* anchor   = (const float*)d_in[0];
    const float* positive = (const float*)d_in[1];
    const float* negative = (const float*)d_in[2];
    const float* outputs  = (const float*)d_in[3];
    const int*   la       = (const int*)d_in[4];
    const int*   ln       = (const int*)d_in[5];
    const float* ex       = (const float*)d_in[6];
    float* out = (float*)d_out;
    float* ws  = (float*)d_ws;

    unsigned short* Abf = (unsigned short*)(ws + OFF_ABF);
    unsigned short* Ebf = (unsigned short*)(ws + OFF_EBF);
    float* esq      = ws + OFF_ESQ;
    float* asq      = ws + OFF_ASQ;
    float* dref     = ws + OFF_DREF;
    float* pmin     = ws + OFF_PMIN;
    float* ce_part  = ws + OFF_CEP;
    float* tr_part  = ws + OFF_TRP;

    hipLaunchKernelGGL(prep_kernel,  dim3(640),  dim3(512),  0, stream,
                       anchor, positive, negative, ex, la, Abf, Ebf, esq, asq, dref, tr_part, pmin);
    hipLaunchKernelGGL(main_kernel,  dim3(1792), dim3(512),  0, stream,
                       Abf, Ebf, asq, esq, outputs, la, ln, pmin, ce_part);
    hipLaunchKernelGGL(final_kernel, dim3(1),    dim3(1024), 0, stream,
                       ce_part, tr_part, pmin, dref, out);
}